// Round 1
// 302.346 us; speedup vs baseline: 1.0319x; 1.0319x over previous
//
#include <hip/hip_runtime.h>

typedef unsigned int uint;
typedef __bf16 bf16_t;
typedef bf16_t bf16x8 __attribute__((ext_vector_type(8)));
typedef float floatx4 __attribute__((ext_vector_type(4)));

struct __align__(8) us4 { unsigned short x, y, z, w; };

__device__ __forceinline__ unsigned short f2b(float f) {
    unsigned u = __float_as_uint(f);
    u = u + 0x7FFFu + ((u >> 16) & 1u);   // RNE
    return (unsigned short)(u >> 16);
}
__device__ __forceinline__ float b2f(unsigned short h) {
    return __uint_as_float(((unsigned)h) << 16);
}

// async global->LDS, 16B per lane; LDS dest is wave-uniform base + lane*16
__device__ __forceinline__ void g2l16(const void* g, void* l) {
    __builtin_amdgcn_global_load_lds((__attribute__((address_space(1))) void*)g,
                                     (__attribute__((address_space(3))) void*)l,
                                     16, 0, 0);
}

// ---------------------------------------------------------------------------
// gemm256: O[m,n] = sum_k A[m,k]*B[n,k], K-stride hardcoded 512 (all call
// sites). 256x256 tile, BK=32, 512 threads = 8 waves (2M x 4N), per-wave
// 128x64 output (acc[8][4]).
//
// Pipeline: 4-deep LDS ring (4 x 32KB = 128KB). While computing tile t,
// tile t+3 is staged via global_load_lds. One s_barrier + counted
// s_waitcnt vmcnt(8) per K-tile (2 tiles = 8 loads always in flight; never
// drains to 0 in steady state). Staging writes only touch the buffer whose
// tile's reads completed before the previous barrier -> race-free.
//
// LDS layout: per buffer, 256 rows x 128B; row r byte c holds (after
// swizzle byte ^= (r&7)<<4): bytes 0..63 = A[row r, k 0..31], bytes
// 64..127 = B[row r, k 0..31]. Staged linear-dest with pre-swizzled
// per-lane SOURCE addresses; ds_read applies the same XOR -> 2-way banks.
//
// Grid: 1-D, XCD swizzle id&7 = XCD, g=id>>3, nt=g%NTN, ms=(g/NTN)*8+xcd.
// BMS: ms decodes (batch = ms&7, mtile = ms>>3) -> batch pinned to XCD.
// MODE 0: bf16 store
// MODE 3: f32 store of acc + R (residual)
// MODE 5: bf16 store of acc*(scale/Sn[row]) + R   (attn: fused q-softmax)
// MODE 4: fused qkv, B=concat(Wq,Wk,Wv)[1536x512]:
//   n0<512    : store exp(acc) -> O (=eq), atomicAdd row sums into Sq[m]
//   512..1023 : store exp(acc) transposed -> O2 (=ekT[b,d,n]), atomicAdd
//               column sums into Sk[b*512+d]
//   >=1024    : store acc transposed -> O3 (=vT[b,e,n])
// ---------------------------------------------------------------------------
template <int MODE, int NTN, bool BMS>
__global__ __launch_bounds__(512, 2) void gemm256(
    const unsigned short* __restrict__ A, const unsigned short* __restrict__ B,
    void* __restrict__ O, const unsigned short* __restrict__ R,
    unsigned short* __restrict__ O2, unsigned short* __restrict__ O3,
    float* __restrict__ Sq, float* __restrict__ Sk,
    const float* __restrict__ Sn,
    int K, long long sB, float scale)
{
    __shared__ __attribute__((aligned(16))) unsigned short Ls[4][16384]; // 128 KB

    const uint id = blockIdx.x;
    const uint xcd = id & 7;
    const uint g = id >> 3;
    const uint nt = g % NTN;
    const uint mg = g / NTN;
    const uint ms = mg * 8 + xcd;

    int bb, arow0;
    if constexpr (BMS) { bb = (int)(ms & 7); arow0 = bb * 4096 + (int)(ms >> 3) * 256; }
    else               { bb = 0;             arow0 = (int)ms * 256; }
    const int n0 = (int)nt * 256;

    const unsigned short* Bb = B + (long long)bb * sB;
    const int tid = threadIdx.x;
    const int l = tid & 63;
    const int w = tid >> 6;

    // ---- staging: thread owns 16B chunk-column lc, rows r0 + {0,64,128,192}
    // LDS chunk p = c*512 + tid  ->  row = c*64 + (tid>>3), slot = tid&7.
    // slot holds logical chunk lc = slot ^ (row&7)  (XOR-swizzle involution).
    const int r0 = tid >> 3;                    // 0..63
    const int lc = (tid & 7) ^ (r0 & 7);        // 0..7; <4 = A-side, >=4 = B-side
    const unsigned short* gsrc = (lc < 4)
        ? A  + (long long)(arow0 + r0) * 512 + lc * 8
        : Bb + (long long)(n0   + r0) * 512 + (lc - 4) * 8;

#define STAGE(bufi, tt) {                                                   \
        const unsigned short* s_ = gsrc + (tt) * 32;                        \
        unsigned short* d_ = &Ls[bufi][0] + tid * 8;                        \
        g2l16(s_,              d_);                                         \
        g2l16(s_ + 64  * 512,  d_ + 4096);                                  \
        g2l16(s_ + 128 * 512,  d_ + 8192);                                  \
        g2l16(s_ + 192 * 512,  d_ + 12288);                                 \
    }

    // ---- fragment addressing (byte offsets within a buffer)
    const int fr = l & 15;
    const int kq = (l >> 4) * 8;
    const int axA = (kq * 2) ^ ((fr & 7) << 4);   // A bytes 0..63, swizzled
    const int axB = axA ^ 64;                     // B bytes 64..127, swizzled
    const int wr = w >> 2;                        // 0..1 : 128-row half
    const int wc = w & 3;                         // 0..3 : 64-col strip

    floatx4 acc[8][4] = {};
    const int NTk = K >> 5;                       // 512 -> 16 K-tiles

    STAGE(0, 0); STAGE(1, 1); STAGE(2, 2);
    asm volatile("s_waitcnt vmcnt(8)" ::: "memory");   // tile 0 landed
    __builtin_amdgcn_s_barrier();

    for (int t = 0; t < NTk; ++t) {
        if (t + 3 < NTk) STAGE((t + 3) & 3, t + 3);

        const char* Lb = (const char*)&Ls[t & 3][0];
        const char* pa = Lb + (wr * 128 + fr) * 128 + axA;
        const char* pb = Lb + (wc * 64  + fr) * 128 + axB;

        bf16x8 af[8], bv[4];
#pragma unroll
        for (int i = 0; i < 8; ++i) af[i] = *(const bf16x8*)(pa + i * 2048);
#pragma unroll
        for (int j = 0; j < 4; ++j) bv[j] = *(const bf16x8*)(pb + j * 2048);

        __builtin_amdgcn_s_setprio(1);
#pragma unroll
        for (int i = 0; i < 8; ++i)
#pragma unroll
            for (int j = 0; j < 4; ++j)
                acc[i][j] = __builtin_amdgcn_mfma_f32_16x16x32_bf16(
                    af[i], bv[j], acc[i][j], 0, 0, 0);
        __builtin_amdgcn_s_setprio(0);

        if (t < NTk - 1) {
            if (t + 3 < NTk)      asm volatile("s_waitcnt vmcnt(8)" ::: "memory");
            else if (t + 2 < NTk) asm volatile("s_waitcnt vmcnt(4)" ::: "memory");
            else                  asm volatile("s_waitcnt vmcnt(0)" ::: "memory");
            __builtin_amdgcn_s_barrier();
        }
    }
#undef STAGE

    // C/D layout (verified m89/m91): col = lane&15, row = (lane>>4)*4 + reg
    const int col = l & 15;
    const int rbase = (l >> 4) * 4;
    const int gm0 = arow0 + wr * 128 + rbase;     // + i*16 + r
    const int gn0 = n0 + wc * 64 + col;           // + j*16

    if constexpr (MODE == 4) {
        if (n0 < 512) {
            // q branch: store exp, row-sum atomics
            unsigned short* Oq = (unsigned short*)O;
            float rs[8][4];
#pragma unroll
            for (int i = 0; i < 8; ++i)
#pragma unroll
                for (int r = 0; r < 4; ++r) rs[i][r] = 0.f;
#pragma unroll
            for (int i = 0; i < 8; ++i) {
                int gm = gm0 + i * 16;
#pragma unroll
                for (int j = 0; j < 4; ++j) {
                    int gn = gn0 + j * 16;
#pragma unroll
                    for (int r = 0; r < 4; ++r) {
                        float e = __expf(acc[i][j][r]);
                        rs[i][r] += e;
                        Oq[(long long)(gm + r) * 512 + gn] = f2b(e);
                    }
                }
            }
#pragma unroll
            for (int i = 0; i < 8; ++i)
#pragma unroll
                for (int r = 0; r < 4; ++r) {
                    float v = rs[i][r];
                    v += __shfl_xor(v, 1);
                    v += __shfl_xor(v, 2);
                    v += __shfl_xor(v, 4);
                    v += __shfl_xor(v, 8);
                    if ((l & 15) == 0)
                        atomicAdd(&Sq[gm0 + i * 16 + r], v);
                }
        } else if (n0 < 1024) {
            // k branch: store exp transposed, column-sum atomics
            const int b = arow0 >> 12;
            const int mq0 = (arow0 & 4095) + wr * 128 + rbase;
            float cs[4] = {0.f, 0.f, 0.f, 0.f};
#pragma unroll
            for (int i = 0; i < 8; ++i) {
                int mq = mq0 + i * 16;
#pragma unroll
                for (int j = 0; j < 4; ++j) {
                    int d = gn0 + j * 16 - 512;
                    float e0 = __expf(acc[i][j][0]);
                    float e1 = __expf(acc[i][j][1]);
                    float e2 = __expf(acc[i][j][2]);
                    float e3 = __expf(acc[i][j][3]);
                    cs[j] += e0 + e1 + e2 + e3;
                    us4 pk = { f2b(e0), f2b(e1), f2b(e2), f2b(e3) };
                    *(us4*)(O2 + ((long long)b * 512 + d) * 4096 + mq) = pk;
                }
            }
#pragma unroll
            for (int j = 0; j < 4; ++j) {
                float v = cs[j];
                v += __shfl_xor(v, 16);
                v += __shfl_xor(v, 32);
                if (l < 16)
                    atomicAdd(&Sk[b * 512 + gn0 + j * 16 - 512], v);
            }
        } else {
            // v branch: plain transposed store
            const int b = arow0 >> 12;
            const int mq0 = (arow0 & 4095) + wr * 128 + rbase;
#pragma unroll
            for (int i = 0; i < 8; ++i) {
                int mq = mq0 + i * 16;
#pragma unroll
                for (int j = 0; j < 4; ++j) {
                    int e_ = gn0 + j * 16 - 1024;
                    us4 pk = { f2b(acc[i][j][0]), f2b(acc[i][j][1]),
                               f2b(acc[i][j][2]), f2b(acc[i][j][3]) };
                    *(us4*)(O3 + ((long long)b * 512 + e_) * 4096 + mq) = pk;
                }
            }
        }
    } else if constexpr (MODE == 5) {
#pragma unroll
        for (int i = 0; i < 8; ++i) {
            int gm = gm0 + i * 16;
            float invs[4];
#pragma unroll
            for (int r = 0; r < 4; ++r) invs[r] = scale / Sn[gm + r];
#pragma unroll
            for (int j = 0; j < 4; ++j) {
                int gn = gn0 + j * 16;
#pragma unroll
                for (int r = 0; r < 4; ++r) {
                    long long idx = (long long)(gm + r) * 512 + gn;
                    ((unsigned short*)O)[idx] =
                        f2b(acc[i][j][r] * invs[r] + b2f(R[idx]));
                }
            }
        }
    } else {
#pragma unroll
        for (int i = 0; i < 8; ++i) {
            int gm = gm0 + i * 16;
#pragma unroll
            for (int j = 0; j < 4; ++j) {
                int gn = gn0 + j * 16;
#pragma unroll
                for (int r = 0; r < 4; ++r) {
                    long long idx = (long long)(gm + r) * 512 + gn;
                    float v = acc[i][j][r];
                    if constexpr (MODE == 0) {
                        ((unsigned short*)O)[idx] = f2b(v);
                    } else {
                        ((float*)O)[idx] = v + b2f(R[idx]);
                    }
                }
            }
        }
    }
}

// ---------------------------------------------------------------------------
// ctx split-K gemm (BK=64): partial of ctxT'[b,e,d] = sum_n vT[b,e,n]*ek[b,d,n]
// split-K=4 (K=1024/block). 512 blocks, XCD-pinned per (b,s) K-slice.
// (unchanged this round; next target)
// ---------------------------------------------------------------------------
__global__ __launch_bounds__(256, 4) void ctx_gemm_sk(
    const unsigned short* __restrict__ V, const unsigned short* __restrict__ Kt,
    float* __restrict__ P)
{
    __shared__ __attribute__((aligned(16))) unsigned short As[128 * 64];
    __shared__ __attribute__((aligned(16))) unsigned short Bs[128 * 64];

    const uint id = blockIdx.x;          // 0..511
    const uint xcd = id & 7;
    const uint g = id >> 3;              // 0..63
    const uint sub = g & 15;             // tile within (b,s)
    const int z = (int)(g >> 4) * 8 + (int)xcd;   // 0..31 = b*4+s
    const int b = z >> 2;
    const int s = z & 3;
    const int m0 = (int)(sub >> 2) * 128;
    const int n0 = (int)(sub & 3) * 128;

    const unsigned short* Ab = V  + (long long)b * 512 * 4096 + s * 1024;
    const unsigned short* Bb = Kt + (long long)b * 512 * 4096 + s * 1024;

    const int tid = threadIdx.x;
    const int l = tid & 63;
    const int w = tid >> 6;
    const int wm = (w >> 1) * 64;
    const int wn = (w & 1) * 64;

    const int srow = tid >> 3;
    const int scol = (tid & 7) * 8;
    const unsigned short* ga = Ab + (long long)(m0 + srow) * 4096 + scol;
    const unsigned short* gb = Bb + (long long)(n0 + srow) * 4096 + scol;
    unsigned short* la = As + tid * 8;
    unsigned short* lb = Bs + tid * 8;

    const int fr = l & 15;
    const int kq = (l >> 4) * 8;

    floatx4 acc[4][4] = {};

    for (int kt = 0; kt < 1024; kt += 64) {
        __syncthreads();
#pragma unroll
        for (int c = 0; c < 4; ++c) {
            g2l16(ga + (long long)(c * 32) * 4096, la + c * 2048);
            g2l16(gb + (long long)(c * 32) * 4096, lb + c * 2048);
        }
        ga += 64; gb += 64;
        __syncthreads();

#pragma unroll
        for (int h = 0; h < 2; ++h) {
            bf16x8 af[4], bfr[4];
#pragma unroll
            for (int i = 0; i < 4; ++i) {
                af[i]  = *(const bf16x8*)(As + (wm + i * 16 + fr) * 64 + kq + 32 * h);
                bfr[i] = *(const bf16x8*)(Bs + (wn + i * 16 + fr) * 64 + kq + 32 * h);
            }
#pragma unroll
            for (int i = 0; i < 4; ++i)
#pragma unroll
                for (int j = 0; j < 4; ++j)
                    acc[i][j] = __builtin_amdgcn_mfma_f32_16x16x32_bf16(
                        af[i], bfr[j], acc[i][j], 0, 0, 0);
        }
    }

    const int col = l & 15;
    const int rbase = (l >> 4) * 4;
    float* Pb = P + ((long long)z * 16 + (sub >> 2) * 4 + (sub & 3)) * 16384;
#pragma unroll
    for (int i = 0; i < 4; ++i)
#pragma unroll
        for (int j = 0; j < 4; ++j)
#pragma unroll
            for (int r = 0; r < 4; ++r)
                Pb[(wm + i * 16 + rbase + r) * 128 + wn + j * 16 + col] =
                    acc[i][j][r];
}

// Sum 4 split-K partials, normalize by k-softmax denominator Sk[b*512+d],
// store bf16 ctxT[b, e, d].
__global__ __launch_bounds__(256) void ctx_reduce(const float* __restrict__ P,
                                                  const float* __restrict__ Sk,
                                                  unsigned short* __restrict__ Ct)
{
    long long f = (long long)blockIdx.x * 256 + threadIdx.x;
    long long base = f * 4;
    int tile = (int)(base >> 14);          // (b, mt, nt)
    int lo = (int)(base & 16383);
    int b = tile >> 4;
    int mt = (tile >> 2) & 3;
    int nt = tile & 3;
    float4 s = {0.f, 0.f, 0.f, 0.f};
#pragma unroll
    for (int sp = 0; sp < 4; ++sp) {
        float4 v = *(const float4*)(P + ((long long)(b * 4 + sp) * 16 + mt * 4 + nt) * 16384 + lo);
        s.x += v.x; s.y += v.y; s.z += v.z; s.w += v.w;
    }
    int le = lo >> 7;
    int ld = lo & 127;
    float4 sk = *(const float4*)(Sk + b * 512 + nt * 128 + ld);
    us4 o = { f2b(s.x / sk.x), f2b(s.y / sk.y), f2b(s.z / sk.z), f2b(s.w / sk.w) };
    *(us4*)(Ct + (long long)b * 262144 + (mt * 128 + le) * 512 + nt * 128 + ld) = o;
}

// ---------------------------------------------------------------------------
// conversions / init
// ---------------------------------------------------------------------------
__global__ __launch_bounds__(256) void f32_to_bf16_k(const float* __restrict__ in,
                                                     unsigned short* __restrict__ out)
{
    long long i = ((long long)blockIdx.x * 256 + threadIdx.x) * 4;
    float4 v = *(const float4*)(in + i);
    us4 o = { f2b(v.x), f2b(v.y), f2b(v.z), f2b(v.w) };
    *(us4*)(out + i) = o;
}

struct WPtrs { const float* in[5]; unsigned short* out[5]; };
__global__ __launch_bounds__(256) void conv_weights(WPtrs p)
{
    int which = blockIdx.y;
    long long i = ((long long)blockIdx.x * 256 + threadIdx.x) * 4;
    float4 v = *(const float4*)(p.in[which] + i);
    us4 o = { f2b(v.x), f2b(v.y), f2b(v.z), f2b(v.w) };
    *(us4*)(p.out[which] + i) = o;
}

__global__ __launch_bounds__(256) void zero_f32(float* __restrict__ p)
{
    long long i = ((long long)blockIdx.x * 256 + threadIdx.x) * 4;
    *(float4*)(p + i) = make_float4(0.f, 0.f, 0.f, 0.f);
}

// ---------------------------------------------------------------------------
extern "C" void kernel_launch(void* const* d_in, const int* in_sizes, int n_in,
                              void* d_out, int out_size, void* d_ws, size_t ws_size,
                              hipStream_t stream)
{
    (void)in_sizes; (void)n_in; (void)out_size; (void)ws_size;
    const float* x  = (const float*)d_in[0];
    const float* Wq = (const float*)d_in[1];
    const float* Wk = (const float*)d_in[2];
    const float* Wv = (const float*)d_in[3];
    const float* W1 = (const float*)d_in[4];
    const float* W2 = (const float*)d_in[5];
    float* out = (float*)d_out;

    const int Bn = 8, N = 4096, C = 512;
    const long long M  = (long long)Bn * N;   // 32768
    const long long XE = M * C;               // 16,777,216 elements

    char* ws = (char*)d_ws;
    size_t off = 0;
    auto carve = [&](size_t bytes) -> void* {
        void* p = ws + off;
        off += (bytes + 255) & ~(size_t)255;
        return p;
    };

    unsigned short* xb   = (unsigned short*)carve(XE * 2);
    unsigned short* wcat = (unsigned short*)carve((size_t)3 * C * C * 2); // [Wq;Wk;Wv]
    unsigned short* w1b  = (unsigned short*)carve((size_t)C * C * 2);
    unsigned short* w2b  = (unsigned short*)carve((size_t)C * C * 2);
    unsigned short* q    = (unsigned short*)carve(XE * 2);   // exp(q)
    unsigned short* kT   = (unsigned short*)carve(XE * 2);   // exp(k) [b,d,n]
    unsigned short* vT   = (unsigned short*)carve(XE * 2);   // [b,e,n]
    unsigned short* ctxT = (unsigned short*)carve((size_t)Bn * C * C * 2); // [b,e,d]
    float* Ssum = (float*)carve((size_t)(M + Bn * C) * 4);   // Sq[M] ++ Sk[Bn*C]
    float* Sq = Ssum;
    float* Sk = Ssum + M;
    unsigned short* xr = kT;       // alias: kT dead after ctx gemm
    unsigned short* h  = vT;       // alias: vT dead after ctx gemm
    float* P = (float*)d_out;      // split-K partials: d_out is scratch until
                                   // the final gemm overwrites all of it

    // zero softmax-sum accumulators (36864 floats = 36 blocks x 256 x 4)
    zero_f32<<<dim3(36), 256, 0, stream>>>(Ssum);

    // dtype conversions
    f32_to_bf16_k<<<dim3((unsigned)(XE / 1024)), dim3(256), 0, stream>>>(x, xb);
    WPtrs wp = { { Wq, Wk, Wv, W1, W2 },
                 { wcat, wcat + C * C, wcat + 2 * C * C, w1b, w2b } };
    conv_weights<<<dim3((C * C) / 1024, 5), dim3(256), 0, stream>>>(wp);

    // fused q/k/v + exp + softmax-denominator atomics: M=32768, N=1536
    // grid = 128 m-tiles x 6 n-tiles = 768 (divisible by 8 for XCD swizzle)
    gemm256<4, 6, false><<<dim3(768), 512, 0, stream>>>(
        xb, wcat, q, nullptr, kT, vT, Sq, Sk, nullptr, C, 0, 0.f);

    // ctxT'[b,e,d] = sum_n vT[b,e,n] * ek[b,d,n]  (split-K=4 + reduce w/ 1/Sk)
    ctx_gemm_sk<<<dim3(512), 256, 0, stream>>>(vT, kT, P);
    ctx_reduce<<<dim3(2048), 256, 0, stream>>>(P, Sk, ctxT);

    // xr[b,n,e] = (scale/Sq[n]) * sum_d eq[b,n,d]*ctxT[b,e,d] + x[b,n,e]
    gemm256<5, 2, true><<<dim3(256), 512, 0, stream>>>(
        q, ctxT, xr, xb, nullptr, nullptr, nullptr, nullptr, Sq,
        C, (long long)C * C, 0.044194173824159216f);

    // h = xr @ W1.T
    gemm256<0, 2, false><<<dim3(256), 512, 0, stream>>>(
        xr, w1b, h, nullptr, nullptr, nullptr, nullptr, nullptr, nullptr,
        C, 0, 0.f);

    // out = h @ W2.T + xr   (fp32 output)
    gemm256<3, 2, false><<<dim3(256), 512, 0, stream>>>(
        h, w2b, out, xr, nullptr, nullptr, nullptr, nullptr, nullptr,
        C, 0, 0.f);
}